// Round 12
// baseline (156.607 us; speedup 1.0000x reference)
//
#include <hip/hip_runtime.h>
#include <hip/hip_bf16.h>

#define SEQ 2048
#define DMODEL 1024
#define NHEAD 16
#define HDIM 64
#define DPOS 64
#define BATCH 2

constexpr float EVENT_HORIZON = 1e-6f;
constexpr float MAX_FORCE = 50.0f;
constexpr float CURV = 0.15f;
constexpr float LOG2E = 1.44269504f;
// P = exp2(min(f,50)*log2e - S2), S2 = 39*log2e: e <= 2^15.87 = 59847 (fp16-safe),
// ratio-invariant under softmax normalization.
constexpr float SHIFT = 39.0f;

typedef __attribute__((ext_vector_type(8))) short frag8;        // 8 bf16/ushort
typedef __attribute__((ext_vector_type(4))) unsigned int uint4v;
typedef __attribute__((ext_vector_type(8))) _Float16 half8;     // 8 fp16
typedef __attribute__((ext_vector_type(2))) _Float16 half2t;    // 2 fp16
typedef __attribute__((ext_vector_type(4))) float frag4f;       // 4 fp32 (C/D)

union A8u { half8 v; half2t h[4]; };

__device__ inline short bfbits(float f) {
  __hip_bfloat16 h = __float2bfloat16(f);
  return *reinterpret_cast<short*>(&h);
}
__device__ inline float fbits(unsigned u) {
  union { unsigned u; float f; } c; c.u = u; return c.f;
}
__device__ inline half2t pkrtz(float a, float b) {
  return __builtin_bit_cast(half2t, __builtin_amdgcn_cvt_pkrtz(a, b));
}
// native 2^x, single v_exp_f32 (no hidden *log2e mul like __expf)
__device__ inline float exp2_fast(float x) {
  float r;
  asm("v_exp_f32 %0, %1" : "=v"(r) : "v"(x));
  return r;
}
// XOR swizzle in 16B units: row = 8 units (128B); b128 frag reads (fixed unit,
// 16 consecutive rows) and staging writes both cover banks <=2-way (free).
__device__ inline int swz(int row, int u) { return row * 8 + (u ^ (row & 7)); }

// ---------------------------------------------------------------------------
// Fused prep: role A (2048 blocks) transpose x -> xt fp16 + masses;
// role B (1024 blocks) invdist with symmetry (upper triangle, dual write);
// role C (1024 blocks) Wout fp32 -> fp16 one-shot (so out_gemm's hot loop
// has zero cvt and half the B bytes — the old fused-cvt ran 32x over).
// ---------------------------------------------------------------------------
__global__ __launch_bounds__(256) void prep_and_dist(
    const float* __restrict__ x, const float* __restrict__ Wm,
    const float* __restrict__ pos, const float* __restrict__ Wout,
    _Float16* __restrict__ xt, float* __restrict__ masses,
    unsigned short* __restrict__ invd, _Float16* __restrict__ wh) {
  __shared__ float Li[64 * 68];
  __shared__ float Lj[64 * 68];
  int bid = blockIdx.x;
  int t = threadIdx.x;

  if (bid >= 3072) {
    // ---- role C: Wout fp32 -> fp16 ----
    int i = (bid - 3072) * 256 + t;
    float4 v = ((const float4*)Wout)[i];
    _Float16 o[4] = {(_Float16)v.x, (_Float16)v.y, (_Float16)v.z, (_Float16)v.w};
    *(float2*)(wh + 4 * (size_t)i) = *(float2*)o;
    return;
  }

  if (bid < 2048) {
    // ---- role A: prep_xt_masses ----
    int bh = bid & 31;
    int h = bh & 15, b = bh >> 4;
    int d = t & 63;
    int jg = (t >> 6) + ((bid >> 5) << 2);   // j-group of 8, 0..255
    int j0 = jg * 8;
    const float* src = x + (size_t)(b * SEQ) * DMODEL + h * HDIM + d;
    float wmd = Wm[h * HDIM + d];
    half8 v;
    float fv[8];
#pragma unroll
    for (int jj = 0; jj < 8; ++jj) {
      float f = src[(size_t)(j0 + jj) * DMODEL];
      fv[jj] = f;
      v[jj] = (_Float16)f;
    }
    *(half8*)(xt + ((size_t)bh * HDIM + d) * SEQ + j0) = v;

    float msum = 0.f;
#pragma unroll
    for (int jj = 0; jj < 8; ++jj) {
      float s = fv[jj] * wmd;
#pragma unroll
      for (int off = 32; off; off >>= 1) s += __shfl_xor(s, off, 64);
      if (d == jj) msum = s;      // lane jj keeps row j0+jj's dot
    }
    if (d < 8) {
      float m = (msum > 20.f) ? msum : log1pf(expf(msum));
      masses[(size_t)bh * SEQ + j0 + d] = m;
    }
    return;
  }

  // ---- role B: invdist (upper triangle only, dual write) ----
  int ib = bid - 2048;
  int i0 = (ib >> 5) * 64, j0 = (ib & 31) * 64;
  if (i0 > j0) return;                       // symmetry: skip lower triangle

  int kk = (t & 15) * 4;
  int rr = t >> 4;
#pragma unroll
  for (int q = 0; q < 4; ++q) {
    int row = q * 16 + rr;
    float4 a = *(const float4*)(pos + (size_t)(i0 + row) * DPOS + kk);
    float4 b = *(const float4*)(pos + (size_t)(j0 + row) * DPOS + kk);
    Li[(kk + 0) * 68 + row] = a.x; Li[(kk + 1) * 68 + row] = a.y;
    Li[(kk + 2) * 68 + row] = a.z; Li[(kk + 3) * 68 + row] = a.w;
    Lj[(kk + 0) * 68 + row] = b.x; Lj[(kk + 1) * 68 + row] = b.y;
    Lj[(kk + 2) * 68 + row] = b.z; Lj[(kk + 3) * 68 + row] = b.w;
  }
  __syncthreads();

  int ti = (t >> 4) * 4;
  int tj = (t & 15) * 4;

  float acc[4][4];
#pragma unroll
  for (int a = 0; a < 4; ++a)
#pragma unroll
    for (int b = 0; b < 4; ++b) acc[a][b] = 0.f;

#pragma unroll 8
  for (int k = 0; k < 64; ++k) {
    float4 a = *(const float4*)(&Li[k * 68 + ti]);
    float4 b = *(const float4*)(&Lj[k * 68 + tj]);
    float av[4] = {a.x, a.y, a.z, a.w};
    float bv[4] = {b.x, b.y, b.z, b.w};
#pragma unroll
    for (int mi = 0; mi < 4; ++mi)
#pragma unroll
      for (int mj = 0; mj < 4; ++mj) {
        float d = av[mi] - bv[mj];
        acc[mi][mj] += d * d;
      }
  }

  unsigned short op[4][4];
#pragma unroll
  for (int mi = 0; mi < 4; ++mi) {
#pragma unroll
    for (int mj = 0; mj < 4; ++mj) {
      float d2 = acc[mi][mj];
      float dn = sqrtf(d2 + EVENT_HORIZON);
      float wv = d2 * (1.f + CURV * __cosf(dn));
      op[mi][mj] = (unsigned short)bfbits(1.0f / fmaxf(wv, EVENT_HORIZON));
    }
    ushort4 o = {op[mi][0], op[mi][1], op[mi][2], op[mi][3]};
    *(ushort4*)(&invd[(size_t)(i0 + ti + mi) * SEQ + j0 + tj]) = o;
  }
  // transposed tile write (thread already holds the 4x4)
#pragma unroll
  for (int mj = 0; mj < 4; ++mj) {
    ushort4 o = {op[0][mj], op[1][mj], op[2][mj], op[3][mj]};
    *(ushort4*)(&invd[(size_t)(j0 + tj + mj) * SEQ + i0 + ti]) = o;
  }
}

// ---------------------------------------------------------------------------
// Kernel 3: fused gravitational attention, fp16 MFMA PV. r12 = r11 frozen
// (structural floor: r2/r6/r9/r11 schedule variants all ~50 us). 128-j
// super-chunks, 256 thr = 4 waves x 16 i-rows, grid 1024 XCD-clustered,
// (256,4) -> VGPR cap 64 (cap law: 256/min_waves_per_EU).
// ---------------------------------------------------------------------------
__global__ __launch_bounds__(256, 4) void attn_mfma_kernel(
    const _Float16* __restrict__ xt, const float* __restrict__ masses,
    const unsigned short* __restrict__ invd, const float* __restrict__ G,
    _Float16* __restrict__ attnout) {
  __shared__ _Float16 Vs[2][2][64 * 64];  // [buf][sub], 8 KB each, swizzled
  __shared__ float Ms[2][128];            // [buf], masses for 128 j

  constexpr float S2 = SHIFT * LOG2E;                 // 56.265
  constexpr float C2 = (MAX_FORCE - SHIFT) * LOG2E;   // 15.870

  int bid = blockIdx.x;
  int bh = (bid & 7) * 4 + ((bid >> 3) & 3);   // XCD-clustered: 4 bh per XCD
  int iblk = bid >> 5;
  int h = bh & (NHEAD - 1), b = bh >> 4;
  int i0 = iblk * 64;
  int t = threadIdx.x, w = t >> 6, lane = t & 63;
  int l15 = lane & 15, quad = lane >> 4;
  int iw = i0 + w * 16;

  float gabs = fabsf(G[h]);
  const float* mrow = masses + (size_t)bh * SEQ;
  float cm = gabs * mrow[iw + l15] * LOG2E;           // row scalar, log2 domain
  const unsigned short* ivrow = invd + (size_t)(iw + l15) * SEQ;

  // staging role: thread t -> d-row t>>2, 16B-units {2*(t&3), 2*(t&3)+1}
  int srow = t >> 2, sunit = (t & 3) * 2;
  const _Float16* srcrow =
      xt + ((size_t)bh * HDIM + srow) * SEQ + sunit * 8;
  int swzoff0 = swz(srow, sunit) * 8;
  int swzoff1 = swz(srow, sunit + 1) * 8;

  half8 vone;
#pragma unroll
  for (int k = 0; k < 8; ++k) vone[k] = (_Float16)1.f;

  frag4f acc[4];
#pragma unroll
  for (int nt = 0; nt < 4; ++nt) acc[nt] = (frag4f)0.f;
  frag4f accs = (frag4f)0.f;          // row sums (every column identical)

  // ---- prologue: super-chunk 0 (j 0..127) ----
  *(half8*)(&Vs[0][0][0] + swzoff0) = *(const half8*)(srcrow);
  *(half8*)(&Vs[0][0][0] + swzoff1) = *(const half8*)(srcrow + 8);
  *(half8*)(&Vs[0][1][0] + swzoff0) = *(const half8*)(srcrow + 64);
  *(half8*)(&Vs[0][1][0] + swzoff1) = *(const half8*)(srcrow + 72);
  if (t < 128) Ms[0][t] = mrow[t];
  frag8 iv_cur[4], iv_nxt[4];
  iv_cur[0] = *(const frag8*)(ivrow + quad * 8);
  iv_cur[1] = *(const frag8*)(ivrow + 32 + quad * 8);
  iv_cur[2] = *(const frag8*)(ivrow + 64 + quad * 8);
  iv_cur[3] = *(const frag8*)(ivrow + 96 + quad * 8);
  __syncthreads();

  for (int cc = 0; cc < 8; ++cc) {
#pragma unroll
    for (int u = 0; u < 2; ++u) {
      int c = cc * 2 + u;               // super-chunk index; u compile-time
      int jn = (c + 1) * 128;
      half8 vpre0, vpre1, vpre2, vpre3;
      float mload = 0.f;

      // ---- burst 1: prefetch sub0 of chunk c+1 ----
      if (c < 15) {
        vpre0 = *(const half8*)(srcrow + jn);
        vpre1 = *(const half8*)(srcrow + jn + 8);
        if (t < 128) mload = mrow[jn + t];
        iv_nxt[0] = *(const frag8*)(ivrow + jn + quad * 8);
        iv_nxt[1] = *(const frag8*)(ivrow + jn + 32 + quad * 8);
      }

      const float* Mbase = &Ms[u][0];
      auto unit = [&](const _Float16* Vb, int sub, int kh, frag8 ivv) {
        const float* mp = Mbase + sub * 64 + kh * 32 + quad * 8;
        float4 mjl = *(const float4*)(mp);
        float4 mjh = *(const float4*)(mp + 4);
        float mjf[8] = {mjl.x, mjl.y, mjl.z, mjl.w,
                        mjh.x, mjh.y, mjh.z, mjh.w};
        uint4v uv = __builtin_bit_cast(uint4v, ivv);
        float e[8];
#pragma unroll
        for (int p = 0; p < 4; ++p) {
          float ivA = fbits(uv[p] << 16);          // even j: low bf16
          float ivB = fbits(uv[p] & 0xffff0000u);  // odd j: high bf16
          float fA = fmaf(cm * mjf[2 * p], ivA, -S2);
          float fB = fmaf(cm * mjf[2 * p + 1], ivB, -S2);
          e[2 * p] = exp2_fast(fminf(fA, C2));
          e[2 * p + 1] = exp2_fast(fminf(fB, C2));
        }
        A8u A;
#pragma unroll
        for (int p = 0; p < 4; ++p)
          A.h[p] = pkrtz(e[2 * p], e[2 * p + 1]);

        __builtin_amdgcn_s_setprio(1);
        accs = __builtin_amdgcn_mfma_f32_16x16x32_f16(A.v, vone, accs, 0, 0, 0);
#pragma unroll
        for (int nt = 0; nt < 4; ++nt) {
          half8 Bf = *(const half8*)(Vb + swz(nt * 16 + l15, kh * 4 + quad) * 8);
          acc[nt] = __builtin_amdgcn_mfma_f32_16x16x32_f16(A.v, Bf, acc[nt], 0, 0, 0);
        }
        __builtin_amdgcn_s_setprio(0);
      };

      // ---- compute sub0 ----
      unit(&Vs[u][0][0], 0, 0, iv_cur[0]);
      unit(&Vs[u][0][0], 0, 1, iv_cur[1]);

      // ---- burst 2: prefetch sub1 of chunk c+1 ----
      if (c < 15) {
        vpre2 = *(const half8*)(srcrow + jn + 64);
        vpre3 = *(const half8*)(srcrow + jn + 72);
        iv_nxt[2] = *(const frag8*)(ivrow + jn + 64 + quad * 8);
        iv_nxt[3] = *(const frag8*)(ivrow + jn + 96 + quad * 8);
      }

      // ---- compute sub1 ----
      unit(&Vs[u][1][0], 1, 0, iv_cur[2]);
      unit(&Vs[u][1][0], 1, 1, iv_cur[3]);

      // ---- write prefetches to the other buffer; rotate ----
      if (c < 15) {
        _Float16* Vn = &Vs[u ^ 1][0][0];
        *(half8*)(Vn + swzoff0) = vpre0;
        *(half8*)(Vn + swzoff1) = vpre1;
        *(half8*)(Vn + 4096 + swzoff0) = vpre2;
        *(half8*)(Vn + 4096 + swzoff1) = vpre3;
        if (t < 128) Ms[u ^ 1][t] = mload;
        iv_cur[0] = iv_nxt[0]; iv_cur[1] = iv_nxt[1];
        iv_cur[2] = iv_nxt[2]; iv_cur[3] = iv_nxt[3];
      }
      __syncthreads();
    }
  }

  // ---- normalize + store (accs[reg] already holds row r = quad*4+reg) ----
#pragma unroll
  for (int reg = 0; reg < 4; ++reg) {
    int r = quad * 4 + reg;            // C/D row within 16x16 tile
    float s = 1.f / accs[reg];
#pragma unroll
    for (int nt = 0; nt < 4; ++nt) {
      attnout[(size_t)(b * SEQ + iw + r) * DMODEL + h * HDIM + nt * 16 + l15] =
          (_Float16)(acc[nt][reg] * s);
    }
  }
}

// ---------------------------------------------------------------------------
// Kernel 4: out = attnout @ wh^T via fp16 MFMA, wh pre-converted (role C).
// r12: hot loop has zero cvt, B-load = one half8/thread/kc. 512 thr = 8
// waves on 128(M)x64(N), each wave 32x32. LDS 48 KB -> 3 blocks/CU. 1D grid
// with XCD-clustered decode: each XCD owns 4 contiguous m-blocks x all n
// (A-slice 1 MB + B 2 MB fits per-XCD L2). (512,4) -> VGPR cap 64.
// ---------------------------------------------------------------------------
__global__ __launch_bounds__(512, 4) void out_gemm_mfma(
    const _Float16* __restrict__ Ag, const _Float16* __restrict__ Wg,
    float* __restrict__ C) {
  __shared__ _Float16 As[2][128 * 64];   // 16 KB each
  __shared__ _Float16 Bs[2][64 * 64];    // 8 KB each

  int bid = blockIdx.x;
  int xcd = bid & 7, local = bid >> 3;       // 64 blocks per XCD
  int m0 = (xcd * 4 + (local >> 4)) * 128;   // 4 contiguous m-blocks per XCD
  int n0 = (local & 15) * 64;

  int t = threadIdx.x, w = t >> 6, lane = t & 63;
  int l15 = lane & 15, quad = lane >> 4;
  int mh = (w >> 1) * 32, nh = (w & 1) * 32;

  int ar = t >> 2;  int au = (t & 3) * 2;   // A: row 0..127, units {au,au+1}
  int br = t >> 3;  int bu = t & 7;         // B: row 0..63, unit bu
  const _Float16* abase = Ag + (size_t)(m0 + ar) * DMODEL + au * 8;
  const _Float16* wbase = Wg + (size_t)(n0 + br) * DMODEL + bu * 8;

  frag4f acc[2][2];
#pragma unroll
  for (int mt = 0; mt < 2; ++mt)
#pragma unroll
    for (int nt = 0; nt < 2; ++nt) acc[mt][nt] = (frag4f)0.f;

  half8 a0, a1, b0;
  auto loadk = [&](int kc) {
    const _Float16* ap = abase + kc * 64;
    a0 = *(const half8*)(ap);
    a1 = *(const half8*)(ap + 8);
    b0 = *(const half8*)(wbase + kc * 64);
  };
  auto stage = [&](int buf) {
    _Float16* aw = As[buf]; _Float16* bw = Bs[buf];
    *(half8*)(aw + swz(ar, au + 0) * 8) = a0;
    *(half8*)(aw + swz(ar, au + 1) * 8) = a1;
    *(half8*)(bw + swz(br, bu) * 8) = b0;
  };

  loadk(0);
  stage(0);
  __syncthreads();

  for (int kk = 0; kk < 8; ++kk) {
#pragma unroll
    for (int u = 0; u < 2; ++u) {
      int kc = kk * 2 + u;              // buf index u is compile-time
      if (kc < 15) loadk(kc + 1);

      const _Float16* ac = As[u];
      const _Float16* bc = Bs[u];
#pragma unroll
      for (int kh = 0; kh < 2; ++kh) {
        half8 Af[2], Bf[2];
#pragma unroll
        for (int mt = 0; mt < 2; ++mt)
          Af[mt] = *(const half8*)(ac + swz(mh + mt * 16 + l15, kh * 4 + quad) * 8);
#pragma unroll
        for (int nt = 0; nt < 2; ++nt)
          Bf[nt] = *(const half8*)(bc + swz(nh + nt * 16 + l15, kh * 4 + quad) * 8);
        __builtin_amdgcn_s_setprio(1);
#pragma unroll
        for (int mt = 0; mt < 2; ++mt)
#pragma unroll
          for (int nt = 0; nt < 2; ++nt)
            acc[mt][nt] = __builtin_amdgcn_mfma_f32_16x16x32_f16(Af[mt], Bf[nt], acc[mt][nt], 0, 0, 0);
        __builtin_amdgcn_s_setprio(0);
      }

      if (kc < 15) stage(u ^ 1);
      __syncthreads();
    }
  }

#pragma unroll
  for (int mt = 0; mt < 2; ++mt)
#pragma unroll
    for (int nt = 0; nt < 2; ++nt)
#pragma unroll
      for (int reg = 0; reg < 4; ++reg) {
        int m = m0 + mh + mt * 16 + quad * 4 + reg;
        int n = n0 + nh + nt * 16 + l15;
        C[(size_t)m * DMODEL + n] = acc[mt][nt][reg];
      }
}

// ---------------------------------------------------------------------------
extern "C" void kernel_launch(void* const* d_in, const int* in_sizes, int n_in,
                              void* d_out, int out_size, void* d_ws, size_t ws_size,
                              hipStream_t stream) {
  const float* x    = (const float*)d_in[0];
  const float* pos  = (const float*)d_in[1];
  const float* Wm   = (const float*)d_in[2];
  const float* G    = (const float*)d_in[3];
  const float* Wout = (const float*)d_in[4];
  float* out = (float*)d_out;

  char* wsb = (char*)d_ws;
  float* masses = (float*)wsb;                                    // 256 KB
  unsigned short* invd = (unsigned short*)(wsb + (1 << 18));      // 8 MB
  _Float16* attnout = (_Float16*)(wsb + (1 << 18) + (8 << 20));   // 8 MB
  _Float16* xt      = (_Float16*)(wsb + (1 << 18) + (16 << 20));  // 8 MB
  _Float16* wh      = (_Float16*)(wsb + (1 << 18) + (24 << 20));  // 2 MB

  prep_and_dist<<<dim3(4096), 256, 0, stream>>>(
      x, Wm, pos, Wout, xt, masses, invd, wh);
  attn_mfma_kernel<<<dim3(1024), 256, 0, stream>>>(
      xt, masses, invd, G, attnout);
  out_gemm_mfma<<<dim3(512), 512, 0, stream>>>(attnout, wh, out);
}

// Round 13
// 150.667 us; speedup vs baseline: 1.0394x; 1.0394x over previous
//
#include <hip/hip_runtime.h>
#include <hip/hip_bf16.h>

#define SEQ 2048
#define DMODEL 1024
#define NHEAD 16
#define HDIM 64
#define DPOS 64
#define BATCH 2

constexpr float EVENT_HORIZON = 1e-6f;
constexpr float MAX_FORCE = 50.0f;
constexpr float CURV = 0.15f;
constexpr float LOG2E = 1.44269504f;
// P = exp2(min(f,50)*log2e - S2), S2 = 39*log2e: e <= 2^15.87 = 59847 (fp16-safe),
// ratio-invariant under softmax normalization.
constexpr float SHIFT = 39.0f;

typedef __attribute__((ext_vector_type(8))) short frag8;        // 8 bf16/ushort
typedef __attribute__((ext_vector_type(4))) unsigned int uint4v;
typedef __attribute__((ext_vector_type(8))) _Float16 half8;     // 8 fp16
typedef __attribute__((ext_vector_type(2))) _Float16 half2t;    // 2 fp16
typedef __attribute__((ext_vector_type(4))) float frag4f;       // 4 fp32 (C/D)

union A8u { half8 v; half2t h[4]; };

__device__ inline short bfbits(float f) {
  __hip_bfloat16 h = __float2bfloat16(f);
  return *reinterpret_cast<short*>(&h);
}
__device__ inline float fbits(unsigned u) {
  union { unsigned u; float f; } c; c.u = u; return c.f;
}
__device__ inline half2t pkrtz(float a, float b) {
  return __builtin_bit_cast(half2t, __builtin_amdgcn_cvt_pkrtz(a, b));
}
// native 2^x, single v_exp_f32 (no hidden *log2e mul like __expf)
__device__ inline float exp2_fast(float x) {
  float r;
  asm("v_exp_f32 %0, %1" : "=v"(r) : "v"(x));
  return r;
}
// packed max of two u32s holding 2x positive bf16 each (positive floats
// compare correctly as i16)
__device__ inline unsigned pkmax(unsigned a, unsigned b) {
  unsigned d;
  asm("v_pk_max_i16 %0, %1, %2" : "=v"(d) : "v"(a), "v"(b));
  return d;
}
// XOR swizzle in 16B units: row = 8 units (128B); b128 frag reads (fixed unit,
// 16 consecutive rows) and staging writes both cover banks <=2-way (free).
__device__ inline int swz(int row, int u) { return row * 8 + (u ^ (row & 7)); }

// ---------------------------------------------------------------------------
// Fused prep: role A (2048 blocks) transpose x -> xt fp16 + masses;
// role B (1024 blocks) invdist with symmetry (upper triangle, dual write);
// role C (1024 blocks) Wout fp32 -> fp16 one-shot.
// ---------------------------------------------------------------------------
__global__ __launch_bounds__(256) void prep_and_dist(
    const float* __restrict__ x, const float* __restrict__ Wm,
    const float* __restrict__ pos, const float* __restrict__ Wout,
    _Float16* __restrict__ xt, float* __restrict__ masses,
    unsigned short* __restrict__ invd, _Float16* __restrict__ wh) {
  __shared__ float Li[64 * 68];
  __shared__ float Lj[64 * 68];
  int bid = blockIdx.x;
  int t = threadIdx.x;

  if (bid >= 3072) {
    // ---- role C: Wout fp32 -> fp16 ----
    int i = (bid - 3072) * 256 + t;
    float4 v = ((const float4*)Wout)[i];
    _Float16 o[4] = {(_Float16)v.x, (_Float16)v.y, (_Float16)v.z, (_Float16)v.w};
    *(float2*)(wh + 4 * (size_t)i) = *(float2*)o;
    return;
  }

  if (bid < 2048) {
    // ---- role A: prep_xt_masses ----
    int bh = bid & 31;
    int h = bh & 15, b = bh >> 4;
    int d = t & 63;
    int jg = (t >> 6) + ((bid >> 5) << 2);   // j-group of 8, 0..255
    int j0 = jg * 8;
    const float* src = x + (size_t)(b * SEQ) * DMODEL + h * HDIM + d;
    float wmd = Wm[h * HDIM + d];
    half8 v;
    float fv[8];
#pragma unroll
    for (int jj = 0; jj < 8; ++jj) {
      float f = src[(size_t)(j0 + jj) * DMODEL];
      fv[jj] = f;
      v[jj] = (_Float16)f;
    }
    *(half8*)(xt + ((size_t)bh * HDIM + d) * SEQ + j0) = v;

    float msum = 0.f;
#pragma unroll
    for (int jj = 0; jj < 8; ++jj) {
      float s = fv[jj] * wmd;
#pragma unroll
      for (int off = 32; off; off >>= 1) s += __shfl_xor(s, off, 64);
      if (d == jj) msum = s;      // lane jj keeps row j0+jj's dot
    }
    if (d < 8) {
      float m = (msum > 20.f) ? msum : log1pf(expf(msum));
      masses[(size_t)bh * SEQ + j0 + d] = m;
    }
    return;
  }

  // ---- role B: invdist (upper triangle only, dual write) ----
  int ib = bid - 2048;
  int i0 = (ib >> 5) * 64, j0 = (ib & 31) * 64;
  if (i0 > j0) return;                       // symmetry: skip lower triangle

  int kk = (t & 15) * 4;
  int rr = t >> 4;
#pragma unroll
  for (int q = 0; q < 4; ++q) {
    int row = q * 16 + rr;
    float4 a = *(const float4*)(pos + (size_t)(i0 + row) * DPOS + kk);
    float4 b = *(const float4*)(pos + (size_t)(j0 + row) * DPOS + kk);
    Li[(kk + 0) * 68 + row] = a.x; Li[(kk + 1) * 68 + row] = a.y;
    Li[(kk + 2) * 68 + row] = a.z; Li[(kk + 3) * 68 + row] = a.w;
    Lj[(kk + 0) * 68 + row] = b.x; Lj[(kk + 1) * 68 + row] = b.y;
    Lj[(kk + 2) * 68 + row] = b.z; Lj[(kk + 3) * 68 + row] = b.w;
  }
  __syncthreads();

  int ti = (t >> 4) * 4;
  int tj = (t & 15) * 4;

  float acc[4][4];
#pragma unroll
  for (int a = 0; a < 4; ++a)
#pragma unroll
    for (int b = 0; b < 4; ++b) acc[a][b] = 0.f;

#pragma unroll 8
  for (int k = 0; k < 64; ++k) {
    float4 a = *(const float4*)(&Li[k * 68 + ti]);
    float4 b = *(const float4*)(&Lj[k * 68 + tj]);
    float av[4] = {a.x, a.y, a.z, a.w};
    float bv[4] = {b.x, b.y, b.z, b.w};
#pragma unroll
    for (int mi = 0; mi < 4; ++mi)
#pragma unroll
      for (int mj = 0; mj < 4; ++mj) {
        float d = av[mi] - bv[mj];
        acc[mi][mj] += d * d;
      }
  }

  unsigned short op[4][4];
#pragma unroll
  for (int mi = 0; mi < 4; ++mi) {
#pragma unroll
    for (int mj = 0; mj < 4; ++mj) {
      float d2 = acc[mi][mj];
      float dn = sqrtf(d2 + EVENT_HORIZON);
      float wv = d2 * (1.f + CURV * __cosf(dn));
      op[mi][mj] = (unsigned short)bfbits(1.0f / fmaxf(wv, EVENT_HORIZON));
    }
    ushort4 o = {op[mi][0], op[mi][1], op[mi][2], op[mi][3]};
    *(ushort4*)(&invd[(size_t)(i0 + ti + mi) * SEQ + j0 + tj]) = o;
  }
  // transposed tile write (thread already holds the 4x4)
#pragma unroll
  for (int mj = 0; mj < 4; ++mj) {
    ushort4 o = {op[0][mj], op[1][mj], op[2][mj], op[3][mj]};
    *(ushort4*)(&invd[(size_t)(j0 + tj + mj) * SEQ + i0 + ti]) = o;
  }
}

// ---------------------------------------------------------------------------
// Kernel 3: fused gravitational attention, fp16 MFMA PV.
// r13 = r11 + SPARSITY SKIP: skip a 128-j super-chunk iff the conservative
// bound cm_max * mj_max * iv_max < S2 - 26, which guarantees every fp32
// e-value < 2^-26 -> pkrtz (RTZ) flushes to EXACTLY 0 in fp16 -> the
// chunk's contribution to acc/accs is exactly 0 -> output bit-identical.
// All factors positive (softplus>0, |G|>=0, iv>0); bf16 iv max via packed
// v_pk_max_i16 (positive floats compare as i16). Diagonal chunks have
// iv=1e6 -> bound huge -> never skipped (row sum stays >= 2^15.8).
// Random-gaussian data: ~15/16 chunks skip (~8x less score VALU + MFMA).
// Adversarial data: no skips, ~3% guard overhead. Guard per chunk: ~35 VALU
// (21 pk/fmax tree + 6 shfl + bound).
// ---------------------------------------------------------------------------
__global__ __launch_bounds__(256, 4) void attn_mfma_kernel(
    const _Float16* __restrict__ xt, const float* __restrict__ masses,
    const unsigned short* __restrict__ invd, const float* __restrict__ G,
    _Float16* __restrict__ attnout) {
  __shared__ _Float16 Vs[2][2][64 * 64];  // [buf][sub], 8 KB each, swizzled
  __shared__ float Ms[2][128];            // [buf], masses for 128 j
  __shared__ float Mmax[16];              // per-super-chunk masses max

  constexpr float S2 = SHIFT * LOG2E;                 // 56.265
  constexpr float C2 = (MAX_FORCE - SHIFT) * LOG2E;   // 15.870
  constexpr float THR = S2 - 26.f;                    // skip bound threshold

  int bid = blockIdx.x;
  int bh = (bid & 7) * 4 + ((bid >> 3) & 3);   // XCD-clustered: 4 bh per XCD
  int iblk = bid >> 5;
  int h = bh & (NHEAD - 1), b = bh >> 4;
  int i0 = iblk * 64;
  int t = threadIdx.x, w = t >> 6, lane = t & 63;
  int l15 = lane & 15, quad = lane >> 4;
  int iw = i0 + w * 16;

  float gabs = fabsf(G[h]);
  const float* mrow = masses + (size_t)bh * SEQ;
  float cm = gabs * mrow[iw + l15] * LOG2E;           // row scalar, log2 domain
  const unsigned short* ivrow = invd + (size_t)(iw + l15) * SEQ;

  // wave-max of cm over the 16 rows (lanes with same l15 share cm)
  float cmx = cm;
#pragma unroll
  for (int off = 1; off < 16; off <<= 1) cmx = fmaxf(cmx, __shfl_xor(cmx, off, 64));

  // staging role: thread t -> d-row t>>2, 16B-units {2*(t&3), 2*(t&3)+1}
  int srow = t >> 2, sunit = (t & 3) * 2;
  const _Float16* srcrow =
      xt + ((size_t)bh * HDIM + srow) * SEQ + sunit * 8;
  int swzoff0 = swz(srow, sunit) * 8;
  int swzoff1 = swz(srow, sunit + 1) * 8;

  half8 vone;
#pragma unroll
  for (int k = 0; k < 8; ++k) vone[k] = (_Float16)1.f;

  frag4f acc[4];
#pragma unroll
  for (int nt = 0; nt < 4; ++nt) acc[nt] = (frag4f)0.f;
  frag4f accs = (frag4f)0.f;          // row sums (every column identical)

  // ---- prologue: Mmax table (per-128j masses max; 256 thr x 8 = 2048) ----
  {
    const float* mp = mrow + t * 8;
    float4 q0 = *(const float4*)(mp);
    float4 q1 = *(const float4*)(mp + 4);
    float v0 = fmaxf(fmaxf(fmaxf(q0.x, q0.y), fmaxf(q0.z, q0.w)),
                     fmaxf(fmaxf(q1.x, q1.y), fmaxf(q1.z, q1.w)));
#pragma unroll
    for (int off = 1; off < 16; off <<= 1) v0 = fmaxf(v0, __shfl_xor(v0, off, 64));
    if ((t & 15) == 0) Mmax[t >> 4] = v0;
  }

  // ---- prologue: super-chunk 0 (j 0..127) ----
  *(half8*)(&Vs[0][0][0] + swzoff0) = *(const half8*)(srcrow);
  *(half8*)(&Vs[0][0][0] + swzoff1) = *(const half8*)(srcrow + 8);
  *(half8*)(&Vs[0][1][0] + swzoff0) = *(const half8*)(srcrow + 64);
  *(half8*)(&Vs[0][1][0] + swzoff1) = *(const half8*)(srcrow + 72);
  if (t < 128) Ms[0][t] = mrow[t];
  frag8 iv_cur[4], iv_nxt[4];
  iv_cur[0] = *(const frag8*)(ivrow + quad * 8);
  iv_cur[1] = *(const frag8*)(ivrow + 32 + quad * 8);
  iv_cur[2] = *(const frag8*)(ivrow + 64 + quad * 8);
  iv_cur[3] = *(const frag8*)(ivrow + 96 + quad * 8);
  __syncthreads();

  for (int cc = 0; cc < 8; ++cc) {
#pragma unroll
    for (int u = 0; u < 2; ++u) {
      int c = cc * 2 + u;               // super-chunk index; u compile-time
      int jn = (c + 1) * 128;
      half8 vpre0, vpre1, vpre2, vpre3;
      float mload = 0.f;

      // ---- burst 1: prefetch sub0 of chunk c+1 ----
      if (c < 15) {
        vpre0 = *(const half8*)(srcrow + jn);
        vpre1 = *(const half8*)(srcrow + jn + 8);
        if (t < 128) mload = mrow[jn + t];
        iv_nxt[0] = *(const frag8*)(ivrow + jn + quad * 8);
        iv_nxt[1] = *(const frag8*)(ivrow + jn + 32 + quad * 8);
      }

      // ---- sparsity guard: wave-max of iv over the 128-j chunk ----
      bool live;
      {
        uint4v q0 = __builtin_bit_cast(uint4v, iv_cur[0]);
        uint4v q1 = __builtin_bit_cast(uint4v, iv_cur[1]);
        uint4v q2 = __builtin_bit_cast(uint4v, iv_cur[2]);
        uint4v q3 = __builtin_bit_cast(uint4v, iv_cur[3]);
        unsigned m0 = pkmax(pkmax(q0[0], q1[0]), pkmax(q2[0], q3[0]));
        unsigned m1 = pkmax(pkmax(q0[1], q1[1]), pkmax(q2[1], q3[1]));
        unsigned m2 = pkmax(pkmax(q0[2], q1[2]), pkmax(q2[2], q3[2]));
        unsigned m3 = pkmax(pkmax(q0[3], q1[3]), pkmax(q2[3], q3[3]));
        unsigned r = pkmax(pkmax(m0, m1), pkmax(m2, m3));
        float ivm = fmaxf(fbits(r << 16), fbits(r & 0xffff0000u));
#pragma unroll
        for (int off = 1; off < 64; off <<= 1)
          ivm = fmaxf(ivm, __shfl_xor(ivm, off, 64));
        live = (cmx * Mmax[c] * ivm >= THR);
      }

      const float* Mbase = &Ms[u][0];
      auto unit = [&](const _Float16* Vb, int sub, int kh, frag8 ivv) {
        const float* mp = Mbase + sub * 64 + kh * 32 + quad * 8;
        float4 mjl = *(const float4*)(mp);
        float4 mjh = *(const float4*)(mp + 4);
        float mjf[8] = {mjl.x, mjl.y, mjl.z, mjl.w,
                        mjh.x, mjh.y, mjh.z, mjh.w};
        uint4v uv = __builtin_bit_cast(uint4v, ivv);
        float e[8];
#pragma unroll
        for (int p = 0; p < 4; ++p) {
          float ivA = fbits(uv[p] << 16);          // even j: low bf16
          float ivB = fbits(uv[p] & 0xffff0000u);  // odd j: high bf16
          float fA = fmaf(cm * mjf[2 * p], ivA, -S2);
          float fB = fmaf(cm * mjf[2 * p + 1], ivB, -S2);
          e[2 * p] = exp2_fast(fminf(fA, C2));
          e[2 * p + 1] = exp2_fast(fminf(fB, C2));
        }
        A8u A;
#pragma unroll
        for (int p = 0; p < 4; ++p)
          A.h[p] = pkrtz(e[2 * p], e[2 * p + 1]);

        __builtin_amdgcn_s_setprio(1);
        accs = __builtin_amdgcn_mfma_f32_16x16x32_f16(A.v, vone, accs, 0, 0, 0);
#pragma unroll
        for (int nt = 0; nt < 4; ++nt) {
          half8 Bf = *(const half8*)(Vb + swz(nt * 16 + l15, kh * 4 + quad) * 8);
          acc[nt] = __builtin_amdgcn_mfma_f32_16x16x32_f16(A.v, Bf, acc[nt], 0, 0, 0);
        }
        __builtin_amdgcn_s_setprio(0);
      };

      // ---- compute sub0 (skipped when provably all-zero) ----
      if (live) {
        unit(&Vs[u][0][0], 0, 0, iv_cur[0]);
        unit(&Vs[u][0][0], 0, 1, iv_cur[1]);
      }

      // ---- burst 2: prefetch sub1 of chunk c+1 ----
      if (c < 15) {
        vpre2 = *(const half8*)(srcrow + jn + 64);
        vpre3 = *(const half8*)(srcrow + jn + 72);
        iv_nxt[2] = *(const frag8*)(ivrow + jn + 64 + quad * 8);
        iv_nxt[3] = *(const frag8*)(ivrow + jn + 96 + quad * 8);
      }

      // ---- compute sub1 ----
      if (live) {
        unit(&Vs[u][1][0], 1, 0, iv_cur[2]);
        unit(&Vs[u][1][0], 1, 1, iv_cur[3]);
      }

      // ---- write prefetches to the other buffer; rotate ----
      if (c < 15) {
        _Float16* Vn = &Vs[u ^ 1][0][0];
        *(half8*)(Vn + swzoff0) = vpre0;
        *(half8*)(Vn + swzoff1) = vpre1;
        *(half8*)(Vn + 4096 + swzoff0) = vpre2;
        *(half8*)(Vn + 4096 + swzoff1) = vpre3;
        if (t < 128) Ms[u ^ 1][t] = mload;
        iv_cur[0] = iv_nxt[0]; iv_cur[1] = iv_nxt[1];
        iv_cur[2] = iv_nxt[2]; iv_cur[3] = iv_nxt[3];
      }
      __syncthreads();
    }
  }

  // ---- normalize + store (accs[reg] already holds row r = quad*4+reg) ----
#pragma unroll
  for (int reg = 0; reg < 4; ++reg) {
    int r = quad * 4 + reg;            // C/D row within 16x16 tile
    float s = 1.f / accs[reg];
#pragma unroll
    for (int nt = 0; nt < 4; ++nt) {
      attnout[(size_t)(b * SEQ + iw + r) * DMODEL + h * HDIM + nt * 16 + l15] =
          (_Float16)(acc[nt][reg] * s);
    }
  }
}

// ---------------------------------------------------------------------------
// Kernel 4: out = attnout @ wh^T via fp16 MFMA, wh pre-converted (role C).
// 512 thr = 8 waves on 128(M)x64(N), each wave 32x32. LDS 48 KB -> 3
// blocks/CU. 1D grid, XCD-clustered decode. (512,4) -> VGPR cap 64.
// ---------------------------------------------------------------------------
__global__ __launch_bounds__(512, 4) void out_gemm_mfma(
    const _Float16* __restrict__ Ag, const _Float16* __restrict__ Wg,
    float* __restrict__ C) {
  __shared__ _Float16 As[2][128 * 64];   // 16 KB each
  __shared__ _Float16 Bs[2][64 * 64];    // 8 KB each

  int bid = blockIdx.x;
  int xcd = bid & 7, local = bid >> 3;       // 64 blocks per XCD
  int m0 = (xcd * 4 + (local >> 4)) * 128;   // 4 contiguous m-blocks per XCD
  int n0 = (local & 15) * 64;

  int t = threadIdx.x, w = t >> 6, lane = t & 63;
  int l15 = lane & 15, quad = lane >> 4;
  int mh = (w >> 1) * 32, nh = (w & 1) * 32;

  int ar = t >> 2;  int au = (t & 3) * 2;   // A: row 0..127, units {au,au+1}
  int br = t >> 3;  int bu = t & 7;         // B: row 0..63, unit bu
  const _Float16* abase = Ag + (size_t)(m0 + ar) * DMODEL + au * 8;
  const _Float16* wbase = Wg + (size_t)(n0 + br) * DMODEL + bu * 8;

  frag4f acc[2][2];
#pragma unroll
  for (int mt = 0; mt < 2; ++mt)
#pragma unroll
    for (int nt = 0; nt < 2; ++nt) acc[mt][nt] = (frag4f)0.f;

  half8 a0, a1, b0;
  auto loadk = [&](int kc) {
    const _Float16* ap = abase + kc * 64;
    a0 = *(const half8*)(ap);
    a1 = *(const half8*)(ap + 8);
    b0 = *(const half8*)(wbase + kc * 64);
  };
  auto stage = [&](int buf) {
    _Float16* aw = As[buf]; _Float16* bw = Bs[buf];
    *(half8*)(aw + swz(ar, au + 0) * 8) = a0;
    *(half8*)(aw + swz(ar, au + 1) * 8) = a1;
    *(half8*)(bw + swz(br, bu) * 8) = b0;
  };

  loadk(0);
  stage(0);
  __syncthreads();

  for (int kk = 0; kk < 8; ++kk) {
#pragma unroll
    for (int u = 0; u < 2; ++u) {
      int kc = kk * 2 + u;              // buf index u is compile-time
      if (kc < 15) loadk(kc + 1);

      const _Float16* ac = As[u];
      const _Float16* bc = Bs[u];
#pragma unroll
      for (int kh = 0; kh < 2; ++kh) {
        half8 Af[2], Bf[2];
#pragma unroll
        for (int mt = 0; mt < 2; ++mt)
          Af[mt] = *(const half8*)(ac + swz(mh + mt * 16 + l15, kh * 4 + quad) * 8);
#pragma unroll
        for (int nt = 0; nt < 2; ++nt)
          Bf[nt] = *(const half8*)(bc + swz(nh + nt * 16 + l15, kh * 4 + quad) * 8);
        __builtin_amdgcn_s_setprio(1);
#pragma unroll
        for (int mt = 0; mt < 2; ++mt)
#pragma unroll
          for (int nt = 0; nt < 2; ++nt)
            acc[mt][nt] = __builtin_amdgcn_mfma_f32_16x16x32_f16(Af[mt], Bf[nt], acc[mt][nt], 0, 0, 0);
        __builtin_amdgcn_s_setprio(0);
      }

      if (kc < 15) stage(u ^ 1);
      __syncthreads();
    }
  }

#pragma unroll
  for (int mt = 0; mt < 2; ++mt)
#pragma unroll
    for (int nt = 0; nt < 2; ++nt)
#pragma unroll
      for (int reg = 0; reg < 4; ++reg) {
        int m = m0 + mh + mt * 16 + quad * 4 + reg;
        int n = n0 + nh + nt * 16 + l15;
        C[(size_t)m * DMODEL + n] = acc[mt][nt][reg];
      }
}

// ---------------------------------------------------------------------------
extern "C" void kernel_launch(void* const* d_in, const int* in_sizes, int n_in,
                              void* d_out, int out_size, void* d_ws, size_t ws_size,
                              hipStream_t stream) {
  const float* x    = (const float*)d_in[0];
  const float* pos  = (const float*)d_in[1];
  const float* Wm   = (const float*)d_in[2];
  const float* G    = (const float*)d_in[3];
  const float* Wout = (const float*)d_in[4];
  float* out = (float*)d_out;

  char* wsb = (char*)d_ws;
  float* masses = (float*)wsb;                                    // 256 KB
  unsigned short* invd = (unsigned short*)(wsb + (1 << 18));      // 8 MB
  _Float16* attnout = (_Float16*)(wsb + (1 << 18) + (8 << 20));   // 8 MB
  _Float16* xt      = (_Float16*)(wsb + (1 << 18) + (16 << 20));  // 8 MB
  _Float16* wh      = (_Float16*)(wsb + (1 << 18) + (24 << 20));  // 2 MB

  prep_and_dist<<<dim3(4096), 256, 0, stream>>>(
      x, Wm, pos, Wout, xt, masses, invd, wh);
  attn_mfma_kernel<<<dim3(1024), 256, 0, stream>>>(
      xt, masses, invd, G, attnout);
  out_gemm_mfma<<<dim3(512), 512, 0, stream>>>(attnout, wh, out);
}

// Round 14
// 121.930 us; speedup vs baseline: 1.2844x; 1.2357x over previous
//
#include <hip/hip_runtime.h>
#include <hip/hip_bf16.h>

#define SEQ 2048
#define DMODEL 1024
#define NHEAD 16
#define HDIM 64
#define DPOS 64
#define BATCH 2

constexpr float EVENT_HORIZON = 1e-6f;
constexpr float MAX_FORCE = 50.0f;
constexpr float CURV = 0.15f;
constexpr float LOG2E = 1.44269504f;
// P = exp2(min(f,50)*log2e - S2), S2 = 39*log2e: e <= 2^15.87 = 59847 (fp16-safe),
// ratio-invariant under softmax normalization.
constexpr float SHIFT = 39.0f;

typedef __attribute__((ext_vector_type(8))) short frag8;        // 8 bf16/ushort
typedef __attribute__((ext_vector_type(4))) unsigned int uint4v;
typedef __attribute__((ext_vector_type(8))) _Float16 half8;     // 8 fp16
typedef __attribute__((ext_vector_type(2))) _Float16 half2t;    // 2 fp16
typedef __attribute__((ext_vector_type(4))) float frag4f;       // 4 fp32 (C/D)

union A8u { half8 v; half2t h[4]; };

__device__ inline short bfbits(float f) {
  __hip_bfloat16 h = __float2bfloat16(f);
  return *reinterpret_cast<short*>(&h);
}
__device__ inline float fbits(unsigned u) {
  union { unsigned u; float f; } c; c.u = u; return c.f;
}
__device__ inline half2t pkrtz(float a, float b) {
  return __builtin_bit_cast(half2t, __builtin_amdgcn_cvt_pkrtz(a, b));
}
// native 2^x, single v_exp_f32 (no hidden *log2e mul like __expf)
__device__ inline float exp2_fast(float x) {
  float r;
  asm("v_exp_f32 %0, %1" : "=v"(r) : "v"(x));
  return r;
}
// XOR swizzle in 16B units: row = 8 units (128B); b128 frag reads (fixed unit,
// 16 consecutive rows) and staging writes both cover banks <=2-way (free).
__device__ inline int swz(int row, int u) { return row * 8 + (u ^ (row & 7)); }

// ---------------------------------------------------------------------------
// Fused prep: role A (2048 blocks) transpose x -> xt fp16 + masses;
// role B (1024 blocks) invdist with symmetry (upper triangle, dual write)
// PLUS per-64x64-tile max of the bf16 iv bits -> tilemax[32][32] (liveness
// table for attn's sparsity skip; int-max of positive bf16 == float max,
// computed from the exact bits attn consumes);
// role C (1024 blocks) Wout fp32 -> fp16 one-shot.
// ---------------------------------------------------------------------------
__global__ __launch_bounds__(256) void prep_and_dist(
    const float* __restrict__ x, const float* __restrict__ Wm,
    const float* __restrict__ pos, const float* __restrict__ Wout,
    _Float16* __restrict__ xt, float* __restrict__ masses,
    unsigned short* __restrict__ invd, _Float16* __restrict__ wh,
    float* __restrict__ tilemax) {
  __shared__ float Li[64 * 68];
  __shared__ float Lj[64 * 68];
  int bid = blockIdx.x;
  int t = threadIdx.x;

  if (bid >= 3072) {
    // ---- role C: Wout fp32 -> fp16 ----
    int i = (bid - 3072) * 256 + t;
    float4 v = ((const float4*)Wout)[i];
    _Float16 o[4] = {(_Float16)v.x, (_Float16)v.y, (_Float16)v.z, (_Float16)v.w};
    *(float2*)(wh + 4 * (size_t)i) = *(float2*)o;
    return;
  }

  if (bid < 2048) {
    // ---- role A: prep_xt_masses ----
    int bh = bid & 31;
    int h = bh & 15, b = bh >> 4;
    int d = t & 63;
    int jg = (t >> 6) + ((bid >> 5) << 2);   // j-group of 8, 0..255
    int j0 = jg * 8;
    const float* src = x + (size_t)(b * SEQ) * DMODEL + h * HDIM + d;
    float wmd = Wm[h * HDIM + d];
    half8 v;
    float fv[8];
#pragma unroll
    for (int jj = 0; jj < 8; ++jj) {
      float f = src[(size_t)(j0 + jj) * DMODEL];
      fv[jj] = f;
      v[jj] = (_Float16)f;
    }
    *(half8*)(xt + ((size_t)bh * HDIM + d) * SEQ + j0) = v;

    float msum = 0.f;
#pragma unroll
    for (int jj = 0; jj < 8; ++jj) {
      float s = fv[jj] * wmd;
#pragma unroll
      for (int off = 32; off; off >>= 1) s += __shfl_xor(s, off, 64);
      if (d == jj) msum = s;      // lane jj keeps row j0+jj's dot
    }
    if (d < 8) {
      float m = (msum > 20.f) ? msum : log1pf(expf(msum));
      masses[(size_t)bh * SEQ + j0 + d] = m;
    }
    return;
  }

  // ---- role B: invdist (upper triangle only, dual write) ----
  int ib = bid - 2048;
  int i0 = (ib >> 5) * 64, j0 = (ib & 31) * 64;
  if (i0 > j0) return;                       // symmetry: skip lower triangle

  int kk = (t & 15) * 4;
  int rr = t >> 4;
#pragma unroll
  for (int q = 0; q < 4; ++q) {
    int row = q * 16 + rr;
    float4 a = *(const float4*)(pos + (size_t)(i0 + row) * DPOS + kk);
    float4 b = *(const float4*)(pos + (size_t)(j0 + row) * DPOS + kk);
    Li[(kk + 0) * 68 + row] = a.x; Li[(kk + 1) * 68 + row] = a.y;
    Li[(kk + 2) * 68 + row] = a.z; Li[(kk + 3) * 68 + row] = a.w;
    Lj[(kk + 0) * 68 + row] = b.x; Lj[(kk + 1) * 68 + row] = b.y;
    Lj[(kk + 2) * 68 + row] = b.z; Lj[(kk + 3) * 68 + row] = b.w;
  }
  __syncthreads();

  int ti = (t >> 4) * 4;
  int tj = (t & 15) * 4;

  float acc[4][4];
#pragma unroll
  for (int a = 0; a < 4; ++a)
#pragma unroll
    for (int b = 0; b < 4; ++b) acc[a][b] = 0.f;

#pragma unroll 8
  for (int k = 0; k < 64; ++k) {
    float4 a = *(const float4*)(&Li[k * 68 + ti]);
    float4 b = *(const float4*)(&Lj[k * 68 + tj]);
    float av[4] = {a.x, a.y, a.z, a.w};
    float bv[4] = {b.x, b.y, b.z, b.w};
#pragma unroll
    for (int mi = 0; mi < 4; ++mi)
#pragma unroll
      for (int mj = 0; mj < 4; ++mj) {
        float d = av[mi] - bv[mj];
        acc[mi][mj] += d * d;
      }
  }

  unsigned short op[4][4];
  int mloc = 0;
#pragma unroll
  for (int mi = 0; mi < 4; ++mi) {
#pragma unroll
    for (int mj = 0; mj < 4; ++mj) {
      float d2 = acc[mi][mj];
      float dn = sqrtf(d2 + EVENT_HORIZON);
      float wv = d2 * (1.f + CURV * __cosf(dn));
      op[mi][mj] = (unsigned short)bfbits(1.0f / fmaxf(wv, EVENT_HORIZON));
      mloc = max(mloc, (int)op[mi][mj]);
    }
    ushort4 o = {op[mi][0], op[mi][1], op[mi][2], op[mi][3]};
    *(ushort4*)(&invd[(size_t)(i0 + ti + mi) * SEQ + j0 + tj]) = o;
  }
  // transposed tile write (thread already holds the 4x4)
#pragma unroll
  for (int mj = 0; mj < 4; ++mj) {
    ushort4 o = {op[0][mj], op[1][mj], op[2][mj], op[3][mj]};
    *(ushort4*)(&invd[(size_t)(j0 + tj + mj) * SEQ + i0 + ti]) = o;
  }

  // ---- tile max of bf16 iv bits -> tilemax (both orientations) ----
#pragma unroll
  for (int off = 1; off < 64; off <<= 1)
    mloc = max(mloc, __shfl_xor(mloc, off, 64));
  __syncthreads();                    // Li reads done; safe to reuse
  if ((t & 63) == 0) ((int*)Li)[t >> 6] = mloc;
  __syncthreads();
  if (t == 0) {
    int mm = max(max(((int*)Li)[0], ((int*)Li)[1]),
                 max(((int*)Li)[2], ((int*)Li)[3]));
    float fm = fbits((unsigned)mm << 16);
    int it = ib >> 5, jt = ib & 31;
    tilemax[it * 32 + jt] = fm;
    tilemax[jt * 32 + it] = fm;
  }
}

// ---------------------------------------------------------------------------
// Kernel 3: fused gravitational attention, fp16 MFMA PV.
// r14 = r13 with liveness PRECOMPUTED (off the critical path). Prologue
// builds a 16-bit livemask from tilemax (prep-computed per-tile iv max),
// block-max cm, and per-chunk masses max: live iff cmb*Mmax*ivmax >= THR
// (= S2-26). Bound guarantees every fp32 e < 2^-26 -> pkrtz RTZ flushes to
// EXACTLY 0 in fp16 -> skipped chunk contributes exact zeros -> output
// bit-identical (r13 validated this bound's numerics on HW). Dead chunks
// (15/16 on this data) now skip V prefetch + iv loads + staging + compute:
// cost = scalar branch + barrier. Block-level bound is >= r13's wave-level
// bound -> strictly conservative. Diagonal chunks (iv=1e6) never skip.
// ---------------------------------------------------------------------------
__global__ __launch_bounds__(256, 4) void attn_mfma_kernel(
    const _Float16* __restrict__ xt, const float* __restrict__ masses,
    const unsigned short* __restrict__ invd, const float* __restrict__ G,
    const float* __restrict__ tilemax, _Float16* __restrict__ attnout) {
  __shared__ _Float16 Vs[2][2][64 * 64];  // [buf][sub], 8 KB each, swizzled
  __shared__ float Ms[2][128];            // [buf], masses for 128 j
  __shared__ float Mmax[16];              // per-super-chunk masses max
  __shared__ float CMW[4];                // per-wave cm max
  __shared__ int Lv[16];                  // live flags

  constexpr float S2 = SHIFT * LOG2E;                 // 56.265
  constexpr float C2 = (MAX_FORCE - SHIFT) * LOG2E;   // 15.870
  constexpr float THR = S2 - 26.f;                    // skip bound threshold

  int bid = blockIdx.x;
  int bh = (bid & 7) * 4 + ((bid >> 3) & 3);   // XCD-clustered: 4 bh per XCD
  int iblk = bid >> 5;
  int h = bh & (NHEAD - 1), b = bh >> 4;
  int i0 = iblk * 64;
  int t = threadIdx.x, w = t >> 6, lane = t & 63;
  int l15 = lane & 15, quad = lane >> 4;
  int iw = i0 + w * 16;

  float gabs = fabsf(G[h]);
  const float* mrow = masses + (size_t)bh * SEQ;
  float cm = gabs * mrow[iw + l15] * LOG2E;           // row scalar, log2 domain
  const unsigned short* ivrow = invd + (size_t)(iw + l15) * SEQ;

  // staging role: thread t -> d-row t>>2, 16B-units {2*(t&3), 2*(t&3)+1}
  int srow = t >> 2, sunit = (t & 3) * 2;
  const _Float16* srcrow =
      xt + ((size_t)bh * HDIM + srow) * SEQ + sunit * 8;
  int swzoff0 = swz(srow, sunit) * 8;
  int swzoff1 = swz(srow, sunit + 1) * 8;

  half8 vone;
#pragma unroll
  for (int k = 0; k < 8; ++k) vone[k] = (_Float16)1.f;

  frag4f acc[4];
#pragma unroll
  for (int nt = 0; nt < 4; ++nt) acc[nt] = (frag4f)0.f;
  frag4f accs = (frag4f)0.f;          // row sums (every column identical)

  // ---- prologue: Mmax table (per-128j masses max; 256 thr x 8 = 2048) ----
  {
    const float* mp = mrow + t * 8;
    float4 q0 = *(const float4*)(mp);
    float4 q1 = *(const float4*)(mp + 4);
    float v0 = fmaxf(fmaxf(fmaxf(q0.x, q0.y), fmaxf(q0.z, q0.w)),
                     fmaxf(fmaxf(q1.x, q1.y), fmaxf(q1.z, q1.w)));
#pragma unroll
    for (int off = 1; off < 16; off <<= 1) v0 = fmaxf(v0, __shfl_xor(v0, off, 64));
    if ((t & 15) == 0) Mmax[t >> 4] = v0;
  }
  // per-wave cm max (cm depends on l15 only)
  {
    float cmx = cm;
#pragma unroll
    for (int off = 1; off < 16; off <<= 1) cmx = fmaxf(cmx, __shfl_xor(cmx, off, 64));
    if (lane == 0) CMW[w] = cmx;
  }

  // ---- prologue: stage super-chunk 0 unconditionally ----
  *(half8*)(&Vs[0][0][0] + swzoff0) = *(const half8*)(srcrow);
  *(half8*)(&Vs[0][0][0] + swzoff1) = *(const half8*)(srcrow + 8);
  *(half8*)(&Vs[0][1][0] + swzoff0) = *(const half8*)(srcrow + 64);
  *(half8*)(&Vs[0][1][0] + swzoff1) = *(const half8*)(srcrow + 72);
  if (t < 128) Ms[0][t] = mrow[t];
  frag8 iv_cur[4], iv_nxt[4];
  iv_cur[0] = *(const frag8*)(ivrow + quad * 8);
  iv_cur[1] = *(const frag8*)(ivrow + 32 + quad * 8);
  iv_cur[2] = *(const frag8*)(ivrow + 64 + quad * 8);
  iv_cur[3] = *(const frag8*)(ivrow + 96 + quad * 8);
  __syncthreads();

  // ---- liveness flags from precomputed tilemax ----
  if (t < 16) {
    float cmb = fmaxf(fmaxf(CMW[0], CMW[1]), fmaxf(CMW[2], CMW[3]));
    float ivm = fmaxf(tilemax[iblk * 32 + 2 * t], tilemax[iblk * 32 + 2 * t + 1]);
    Lv[t] = (cmb * Mmax[t] * ivm >= THR) ? 1 : 0;
  }
  __syncthreads();
  unsigned livemask = 0;
#pragma unroll
  for (int c2 = 0; c2 < 16; ++c2)
    livemask |= (unsigned)(Lv[c2] != 0) << c2;
  livemask = __builtin_amdgcn_readfirstlane(livemask);

  for (int cc = 0; cc < 8; ++cc) {
#pragma unroll
    for (int u = 0; u < 2; ++u) {
      int c = cc * 2 + u;               // super-chunk index; u compile-time
      int jn = (c + 1) * 128;
      bool lvc = (livemask >> c) & 1;
      bool lvn = (c < 15) && ((livemask >> (c + 1)) & 1);
      half8 vpre0, vpre1, vpre2, vpre3;
      float mload = 0.f;

      // ---- burst 1: prefetch sub0 of chunk c+1 (only if it's live) ----
      if (lvn) {
        vpre0 = *(const half8*)(srcrow + jn);
        vpre1 = *(const half8*)(srcrow + jn + 8);
        if (t < 128) mload = mrow[jn + t];
        iv_nxt[0] = *(const frag8*)(ivrow + jn + quad * 8);
        iv_nxt[1] = *(const frag8*)(ivrow + jn + 32 + quad * 8);
      }

      const float* Mbase = &Ms[u][0];
      auto unit = [&](const _Float16* Vb, int sub, int kh, frag8 ivv) {
        const float* mp = Mbase + sub * 64 + kh * 32 + quad * 8;
        float4 mjl = *(const float4*)(mp);
        float4 mjh = *(const float4*)(mp + 4);
        float mjf[8] = {mjl.x, mjl.y, mjl.z, mjl.w,
                        mjh.x, mjh.y, mjh.z, mjh.w};
        uint4v uv = __builtin_bit_cast(uint4v, ivv);
        float e[8];
#pragma unroll
        for (int p = 0; p < 4; ++p) {
          float ivA = fbits(uv[p] << 16);          // even j: low bf16
          float ivB = fbits(uv[p] & 0xffff0000u);  // odd j: high bf16
          float fA = fmaf(cm * mjf[2 * p], ivA, -S2);
          float fB = fmaf(cm * mjf[2 * p + 1], ivB, -S2);
          e[2 * p] = exp2_fast(fminf(fA, C2));
          e[2 * p + 1] = exp2_fast(fminf(fB, C2));
        }
        A8u A;
#pragma unroll
        for (int p = 0; p < 4; ++p)
          A.h[p] = pkrtz(e[2 * p], e[2 * p + 1]);

        __builtin_amdgcn_s_setprio(1);
        accs = __builtin_amdgcn_mfma_f32_16x16x32_f16(A.v, vone, accs, 0, 0, 0);
#pragma unroll
        for (int nt = 0; nt < 4; ++nt) {
          half8 Bf = *(const half8*)(Vb + swz(nt * 16 + l15, kh * 4 + quad) * 8);
          acc[nt] = __builtin_amdgcn_mfma_f32_16x16x32_f16(A.v, Bf, acc[nt], 0, 0, 0);
        }
        __builtin_amdgcn_s_setprio(0);
      };

      // ---- compute sub0 (skipped when provably all-zero) ----
      if (lvc) {
        unit(&Vs[u][0][0], 0, 0, iv_cur[0]);
        unit(&Vs[u][0][0], 0, 1, iv_cur[1]);
      }

      // ---- burst 2: prefetch sub1 of chunk c+1 ----
      if (lvn) {
        vpre2 = *(const half8*)(srcrow + jn + 64);
        vpre3 = *(const half8*)(srcrow + jn + 72);
        iv_nxt[2] = *(const frag8*)(ivrow + jn + 64 + quad * 8);
        iv_nxt[3] = *(const frag8*)(ivrow + jn + 96 + quad * 8);
      }

      // ---- compute sub1 ----
      if (lvc) {
        unit(&Vs[u][1][0], 1, 0, iv_cur[2]);
        unit(&Vs[u][1][0], 1, 1, iv_cur[3]);
      }

      // ---- write prefetches to the other buffer; rotate ----
      if (lvn) {
        _Float16* Vn = &Vs[u ^ 1][0][0];
        *(half8*)(Vn + swzoff0) = vpre0;
        *(half8*)(Vn + swzoff1) = vpre1;
        *(half8*)(Vn + 4096 + swzoff0) = vpre2;
        *(half8*)(Vn + 4096 + swzoff1) = vpre3;
        if (t < 128) Ms[u ^ 1][t] = mload;
        iv_cur[0] = iv_nxt[0]; iv_cur[1] = iv_nxt[1];
        iv_cur[2] = iv_nxt[2]; iv_cur[3] = iv_nxt[3];
      }
      __syncthreads();
    }
  }

  // ---- normalize + store (accs[reg] already holds row r = quad*4+reg) ----
#pragma unroll
  for (int reg = 0; reg < 4; ++reg) {
    int r = quad * 4 + reg;            // C/D row within 16x16 tile
    float s = (accs[reg] > 0.f) ? (1.f / accs[reg]) : 0.f;
#pragma unroll
    for (int nt = 0; nt < 4; ++nt) {
      attnout[(size_t)(b * SEQ + iw + r) * DMODEL + h * HDIM + nt * 16 + l15] =
          (_Float16)(acc[nt][reg] * s);
    }
  }
}

// ---------------------------------------------------------------------------
// Kernel 4: out = attnout @ wh^T via fp16 MFMA, wh pre-converted (role C).
// 512 thr = 8 waves on 128(M)x64(N), each wave 32x32. LDS 48 KB -> 3
// blocks/CU. 1D grid, XCD-clustered decode. (512,4) -> VGPR cap 64.
// ---------------------------------------------------------------------------
__global__ __launch_bounds__(512, 4) void out_gemm_mfma(
    const _Float16* __restrict__ Ag, const _Float16* __restrict__ Wg,
    float* __restrict__ C) {
  __shared__ _Float16 As[2][128 * 64];   // 16 KB each
  __shared__ _Float16 Bs[2][64 * 64];    // 8 KB each

  int bid = blockIdx.x;
  int xcd = bid & 7, local = bid >> 3;       // 64 blocks per XCD
  int m0 = (xcd * 4 + (local >> 4)) * 128;   // 4 contiguous m-blocks per XCD
  int n0 = (local & 15) * 64;

  int t = threadIdx.x, w = t >> 6, lane = t & 63;
  int l15 = lane & 15, quad = lane >> 4;
  int mh = (w >> 1) * 32, nh = (w & 1) * 32;

  int ar = t >> 2;  int au = (t & 3) * 2;   // A: row 0..127, units {au,au+1}
  int br = t >> 3;  int bu = t & 7;         // B: row 0..63, unit bu
  const _Float16* abase = Ag + (size_t)(m0 + ar) * DMODEL + au * 8;
  const _Float16* wbase = Wg + (size_t)(n0 + br) * DMODEL + bu * 8;

  frag4f acc[2][2];
#pragma unroll
  for (int mt = 0; mt < 2; ++mt)
#pragma unroll
    for (int nt = 0; nt < 2; ++nt) acc[mt][nt] = (frag4f)0.f;

  half8 a0, a1, b0;
  auto loadk = [&](int kc) {
    const _Float16* ap = abase + kc * 64;
    a0 = *(const half8*)(ap);
    a1 = *(const half8*)(ap + 8);
    b0 = *(const half8*)(wbase + kc * 64);
  };
  auto stage = [&](int buf) {
    _Float16* aw = As[buf]; _Float16* bw = Bs[buf];
    *(half8*)(aw + swz(ar, au + 0) * 8) = a0;
    *(half8*)(aw + swz(ar, au + 1) * 8) = a1;
    *(half8*)(bw + swz(br, bu) * 8) = b0;
  };

  loadk(0);
  stage(0);
  __syncthreads();

  for (int kk = 0; kk < 8; ++kk) {
#pragma unroll
    for (int u = 0; u < 2; ++u) {
      int kc = kk * 2 + u;              // buf index u is compile-time
      if (kc < 15) loadk(kc + 1);

      const _Float16* ac = As[u];
      const _Float16* bc = Bs[u];
#pragma unroll
      for (int kh = 0; kh < 2; ++kh) {
        half8 Af[2], Bf[2];
#pragma unroll
        for (int mt = 0; mt < 2; ++mt)
          Af[mt] = *(const half8*)(ac + swz(mh + mt * 16 + l15, kh * 4 + quad) * 8);
#pragma unroll
        for (int nt = 0; nt < 2; ++nt)
          Bf[nt] = *(const half8*)(bc + swz(nh + nt * 16 + l15, kh * 4 + quad) * 8);
        __builtin_amdgcn_s_setprio(1);
#pragma unroll
        for (int mt = 0; mt < 2; ++mt)
#pragma unroll
          for (int nt = 0; nt < 2; ++nt)
            acc[mt][nt] = __builtin_amdgcn_mfma_f32_16x16x32_f16(Af[mt], Bf[nt], acc[mt][nt], 0, 0, 0);
        __builtin_amdgcn_s_setprio(0);
      }

      if (kc < 15) stage(u ^ 1);
      __syncthreads();
    }
  }

#pragma unroll
  for (int mt = 0; mt < 2; ++mt)
#pragma unroll
    for (int nt = 0; nt < 2; ++nt)
#pragma unroll
      for (int reg = 0; reg < 4; ++reg) {
        int m = m0 + mh + mt * 16 + quad * 4 + reg;
        int n = n0 + nh + nt * 16 + l15;
        C[(size_t)m * DMODEL + n] = acc[mt][nt][reg];
      }
}

// ---------------------------------------------------------------------------
extern "C" void kernel_launch(void* const* d_in, const int* in_sizes, int n_in,
                              void* d_out, int out_size, void* d_ws, size_t ws_size,
                              hipStream_t stream) {
  const float* x    = (const float*)d_in[0];
  const float* pos  = (const float*)d_in[1];
  const float* Wm   = (const float*)d_in[2];
  const float* G    = (const float*)d_in[3];
  const float* Wout = (const float*)d_in[4];
  float* out = (float*)d_out;

  char* wsb = (char*)d_ws;
  float* masses = (float*)wsb;                                    // 256 KB
  unsigned short* invd = (unsigned short*)(wsb + (1 << 18));      // 8 MB
  _Float16* attnout = (_Float16*)(wsb + (1 << 18) + (8 << 20));   // 8 MB
  _Float16* xt      = (_Float16*)(wsb + (1 << 18) + (16 << 20));  // 8 MB
  _Float16* wh      = (_Float16*)(wsb + (1 << 18) + (24 << 20));  // 2 MB
  float* tilemax    = (float*)(wsb + (1 << 18) + (26 << 20));     // 4 KB

  prep_and_dist<<<dim3(4096), 256, 0, stream>>>(
      x, Wm, pos, Wout, xt, masses, invd, wh, tilemax);
  attn_mfma_kernel<<<dim3(1024), 256, 0, stream>>>(
      xt, masses, invd, G, tilemax, attnout);
  out_gemm_mfma<<<dim3(512), 512, 0, stream>>>(attnout, wh, out);
}